// Round 3
// baseline (5610.426 us; speedup 1.0000x reference)
//
#include <hip/hip_runtime.h>
#include <hip/hip_bf16.h>
#include <float.h>

#define NPTS 4096
#define NB 4
#define KNN 20

__device__ __forceinline__ float lrelu(float x) { return x > 0.f ? x : 0.2f * x; }

__device__ __forceinline__ void atomicMaxF(float* addr, float val) {
    int* ia = (int*)addr;
    int old = *ia;
    while (__int_as_float(old) < val) {
        int assumed = old;
        old = atomicCAS(ia, assumed, __float_as_int(val));
        if (old == assumed) break;
    }
}

// ---------------- sq norms for euclid knn ----------------
__global__ void k_sqnorm(const float* __restrict__ x, float* __restrict__ sq) {
    int i = blockIdx.x * 256 + threadIdx.x;   // b*N + n
    int b = i >> 12, n = i & 4095;
    const float* xb = x + b * 6 * NPTS;
    float s = 0.f;
#pragma unroll
    for (int c = 0; c < 6; c++) { float v = xb[c * NPTS + n]; s += v * v; }
    sq[i] = s;
}

// ---------------- euclid knn: 2 queries/block ----------------
__global__ __launch_bounds__(256) void k_knn_euclid(const float* __restrict__ x,
                                                    const float* __restrict__ sq,
                                                    int* __restrict__ idx) {
    __shared__ float dist[2][NPTS];
    __shared__ float qv[2][6];
    __shared__ float sqq[2];
    int t = threadIdx.x;
    int blk = blockIdx.x;
    int b = blk >> 11;               // / 2048
    int q0 = (blk & 2047) * 2;
    const float* xb = x + b * 6 * NPTS;
    const float* sqb = sq + b * NPTS;
    if (t < 12) { int q = t / 6, c = t - q * 6; qv[q][c] = xb[c * NPTS + q0 + q]; }
    if (t < 2) sqq[t] = sqb[q0 + t];
    __syncthreads();
    {
        int q = t >> 7, l = t & 127;
        float c0 = qv[q][0], c1 = qv[q][1], c2 = qv[q][2];
        float c3 = qv[q][3], c4 = qv[q][4], c5 = qv[q][5];
        float sqn = sqq[q];
        for (int it = 0; it < 32; it++) {
            int m = it * 128 + l;
            float dot = c0 * xb[m] + c1 * xb[NPTS + m] + c2 * xb[2 * NPTS + m]
                      + c3 * xb[3 * NPTS + m] + c4 * xb[4 * NPTS + m] + c5 * xb[5 * NPTS + m];
            dist[q][m] = sqn - 2.f * dot + sqb[m];
        }
    }
    __syncthreads();
    int w = t >> 6;
    if (w < 2) {
        int ln = t & 63;
        volatile float* dv = &dist[w][0];     // volatile: mask-write must be re-read each pass
        for (int kk = 0; kk < KNN; kk++) {
            float bv = FLT_MAX; int bm = NPTS;
            for (int j = 0; j < 64; j++) {
                int m = ln + (j << 6);
                float v = dv[m];
                if (v < bv) { bv = v; bm = m; }   // first occurrence keeps smallest m
            }
            for (int off = 32; off > 0; off >>= 1) {
                float ov = __shfl_down(bv, off);
                int   om = __shfl_down(bm, off);
                if (ov < bv || (ov == bv && om < bm)) { bv = ov; bm = om; }
            }
            bm = __shfl(bm, 0);
            if (ln == 0) { idx[(b * NPTS + q0 + w) * KNN + kk] = bm; dv[bm] = FLT_MAX; }
        }
    }
}

// ---------------- cosine knn on normalized 64-ch features ----------------
__global__ __launch_bounds__(256) void k_knn_cos(const float* __restrict__ xn,
                                                 int* __restrict__ idx) {
    __shared__ float dist[2][NPTS];
    __shared__ float qv[2][64];
    int t = threadIdx.x;
    int blk = blockIdx.x;
    int b = blk >> 11;
    int q0 = (blk & 2047) * 2;
    const float* xb = xn + (size_t)b * 64 * NPTS;
    if (t < 128) { int q = t >> 6, c = t & 63; qv[q][c] = xb[c * NPTS + q0 + q]; }
    __syncthreads();
    {
        int q = t >> 7, l = t & 127;
        for (int it = 0; it < 8; it++) {
            int m4 = (it * 128 + l) * 4;
            float ax = 0.f, ay = 0.f, az = 0.f, aw = 0.f;
            const float* p = xb + m4;
#pragma unroll 8
            for (int c = 0; c < 64; c++) {
                float4 v = *(const float4*)(p + c * NPTS);
                float qc = qv[q][c];
                ax += qc * v.x; ay += qc * v.y; az += qc * v.z; aw += qc * v.w;
            }
            float4 r; r.x = ax; r.y = ay; r.z = az; r.w = aw;
            *(float4*)&dist[q][m4] = r;
        }
    }
    __syncthreads();
    int w = t >> 6;
    if (w < 2) {
        int ln = t & 63;
        volatile float* dv = &dist[w][0];
        for (int kk = 0; kk < KNN; kk++) {
            float bv = -FLT_MAX; int bm = NPTS;
            for (int j = 0; j < 64; j++) {
                int m = ln + (j << 6);
                float v = dv[m];
                if (v > bv) { bv = v; bm = m; }
            }
            for (int off = 32; off > 0; off >>= 1) {
                float ov = __shfl_down(bv, off);
                int   om = __shfl_down(bm, off);
                if (ov > bv || (ov == bv && om < bm)) { bv = ov; bm = om; }
            }
            bm = __shfl(bm, 0);
            if (ln == 0) { idx[(b * NPTS + q0 + w) * KNN + kk] = bm; dv[bm] = -FLT_MAX; }
        }
    }
}

// ---------------- normalize 64-ch feature block (batch stride 192*N on input)
__global__ void k_normalize(const float* __restrict__ xin, float* __restrict__ xout) {
    int i = blockIdx.x * 256 + threadIdx.x;   // b*N + n
    int b = i >> 12, n = i & 4095;
    const float* p = xin + (size_t)b * 192 * NPTS + n;
    float s = 0.f;
#pragma unroll
    for (int c = 0; c < 64; c++) { float v = p[c * NPTS]; s += v * v; }
    float inv = 1.f / (sqrtf(s) + 1e-8f);
    float* q = xout + (size_t)b * 64 * NPTS + n;
#pragma unroll
    for (int c = 0; c < 64; c++) q[c * NPTS] = p[c * NPTS] * inv;
}

// ---------------- EdgeConv layer 1: 6ch input, 12 -> 64 -> 64 ----------------
__global__ __launch_bounds__(256) void k_edge1(const float* __restrict__ x,
    const float* __restrict__ w0, const float* __restrict__ s0, const float* __restrict__ o0,
    const float* __restrict__ w1, const float* __restrict__ s1, const float* __restrict__ o1,
    const int* __restrict__ idx, float* __restrict__ out) {
    __shared__ float w0T[12][64];
    __shared__ float w1T[64][64];
    __shared__ float sv0[64], ov0[64], sv1[64], ov1[64];
    __shared__ float ebuf[4][12];
    __shared__ float h0s[4][64];
    int t = threadIdx.x;
    for (int i = t; i < 768; i += 256)  { int oo = i / 12, c = i - oo * 12; w0T[c][oo] = w0[i]; }
    for (int i = t; i < 4096; i += 256) { int oo = i >> 6, c = i & 63;      w1T[c][oo] = w1[i]; }
    if (t < 64) { sv0[t] = s0[t]; ov0[t] = o0[t]; sv1[t] = s1[t]; ov1[t] = o1[t]; }
    int p = t >> 6, o = t & 63;
    int pid = blockIdx.x * 4 + p;
    int b = pid >> 12, n = pid & 4095;
    const float* xb = x + b * 6 * NPTS;
    float cv = 0.f;
    if (o < 6) { cv = xb[o * NPTS + n]; ebuf[p][6 + o] = cv; }
    __syncthreads();
    float acc = -FLT_MAX;
    const int* ib = idx + (b * NPTS + n) * KNN;
    for (int kk = 0; kk < KNN; kk++) {
        int j = ib[kk] & 4095;
        if (o < 6) ebuf[p][o] = xb[o * NPTS + j] - cv;
        __syncthreads();
        float h = 0.f;
#pragma unroll
        for (int c = 0; c < 12; c++) h += w0T[c][o] * ebuf[p][c];
        h = lrelu(h * sv0[o] + ov0[o]);
        h0s[p][o] = h;
        __syncthreads();
        float h2 = 0.f;
#pragma unroll
        for (int c = 0; c < 64; c++) h2 += w1T[c][o] * h0s[p][c];
        h2 = lrelu(h2 * sv1[o] + ov1[o]);
        acc = fmaxf(acc, h2);
        __syncthreads();
    }
    out[(size_t)b * 192 * NPTS + o * NPTS + n] = acc;
}

// ---------------- EdgeConv layers 2/3: 64ch input, 128 -> 64 -> 64 ----------------
__global__ __launch_bounds__(256) void k_edge23(const float* __restrict__ xin,
    const float* __restrict__ w0, const float* __restrict__ s0, const float* __restrict__ o0,
    const float* __restrict__ w1, const float* __restrict__ s1, const float* __restrict__ o1,
    const int* __restrict__ idx, float* __restrict__ out) {
    __shared__ float w0T[128][64];   // 32 KB
    __shared__ float w1T[64][64];    // 16 KB
    __shared__ float sv0[64], ov0[64], sv1[64], ov1[64];
    __shared__ float ebuf[4][128];
    __shared__ float h0s[4][64];
    int t = threadIdx.x;
    for (int i = t; i < 8192; i += 256) { int oo = i >> 7, c = i & 127; w0T[c][oo] = w0[i]; }
    for (int i = t; i < 4096; i += 256) { int oo = i >> 6, c = i & 63;  w1T[c][oo] = w1[i]; }
    if (t < 64) { sv0[t] = s0[t]; ov0[t] = o0[t]; sv1[t] = s1[t]; ov1[t] = o1[t]; }
    int p = t >> 6, o = t & 63;
    int pid = blockIdx.x * 4 + p;
    int b = pid >> 12, n = pid & 4095;
    const float* xb = xin + (size_t)b * 192 * NPTS;
    float cv = xb[o * NPTS + n];
    ebuf[p][64 + o] = cv;            // constant over k
    __syncthreads();
    float acc = -FLT_MAX;
    const int* ib = idx + (b * NPTS + n) * KNN;
    for (int kk = 0; kk < KNN; kk++) {
        int j = ib[kk] & 4095;
        ebuf[p][o] = xb[o * NPTS + j] - cv;
        __syncthreads();
        float h = 0.f;
#pragma unroll
        for (int c = 0; c < 128; c++) h += w0T[c][o] * ebuf[p][c];
        h = lrelu(h * sv0[o] + ov0[o]);
        h0s[p][o] = h;
        __syncthreads();
        float h2 = 0.f;
#pragma unroll
        for (int c = 0; c < 64; c++) h2 += w1T[c][o] * h0s[p][c];
        h2 = lrelu(h2 * sv1[o] + ov1[o]);
        acc = fmaxf(acc, h2);
        __syncthreads();
    }
    out[(size_t)b * 192 * NPTS + o * NPTS + n] = acc;
}

// ---------------- init g to -inf ----------------
__global__ void k_init_g(float* __restrict__ g) {
    g[blockIdx.x * 256 + threadIdx.x] = -FLT_MAX;
}

// ---------------- conv w4 (192->1024) + fused global max pool into g ----------------
__global__ __launch_bounds__(256) void k_w4pool(const float* __restrict__ xc,
                                                const float* __restrict__ w4,
                                                const float* __restrict__ b4,
                                                float* __restrict__ g) {
    __shared__ float wl[8][192];
    __shared__ float bl[8];
    int t = threadIdx.x;
    int obase = blockIdx.y * 8, b = blockIdx.z;
    for (int i = t; i < 8 * 192; i += 256) { int oo = i / 192, c = i - oo * 192; wl[oo][c] = w4[(obase + oo) * 192 + c]; }
    if (t < 8) bl[t] = b4[obase + t];
    __syncthreads();
    int n = blockIdx.x * 256 + t;
    const float* xb = xc + (size_t)b * 192 * NPTS + n;
    float acc[8] = {0, 0, 0, 0, 0, 0, 0, 0};
    for (int c = 0; c < 192; c++) {
        float v = xb[c * NPTS];
#pragma unroll
        for (int oo = 0; oo < 8; oo++) acc[oo] += wl[oo][c] * v;
    }
#pragma unroll
    for (int oo = 0; oo < 8; oo++) {
        float h = lrelu(acc[oo] + bl[oo]);
        for (int off = 32; off > 0; off >>= 1) h = fmaxf(h, __shfl_down(h, off));
        if ((t & 63) == 0) atomicMaxF(&g[b * 1024 + obase + oo], h);
    }
}

// ---------------- goff[b][o] = (wf1[o,192:1216] . g[b]) * sf1[o] + of1[o] ----------------
__global__ __launch_bounds__(256) void k_goff(const float* __restrict__ g,
                                              const float* __restrict__ wf1,
                                              const float* __restrict__ sf1,
                                              const float* __restrict__ of1,
                                              float* __restrict__ goff) {
    int bo = blockIdx.x;                 // b*512 + o
    int b = bo >> 9, o = bo & 511;
    int t = threadIdx.x;
    const float* wr = wf1 + (size_t)o * 1216 + 192;
    const float* gb = g + b * 1024;
    float s = 0.f;
    for (int c = t; c < 1024; c += 256) s += wr[c] * gb[c];
    __shared__ float red[4];
    for (int off = 32; off > 0; off >>= 1) s += __shfl_down(s, off);
    if ((t & 63) == 0) red[t >> 6] = s;
    __syncthreads();
    if (t == 0) {
        float tot = red[0] + red[1] + red[2] + red[3];
        goff[bo] = tot * sf1[o] + of1[o];
    }
}

// ---------------- fused tail: h1(512) -> h2(256) -> out(13) per 16-point tile ----------------
#define TN 16
__global__ __launch_bounds__(256) void k_tail(const float* __restrict__ xc,
                                              const float* __restrict__ wf1,
                                              const float* __restrict__ sf1,
                                              const float* __restrict__ goff,
                                              const float* __restrict__ wf2,
                                              const float* __restrict__ sf2,
                                              const float* __restrict__ of2,
                                              const float* __restrict__ wf3,
                                              float* __restrict__ out) {
    __shared__ float xcs[192][TN];       // 12 KB
    __shared__ float h1s[512][TN + 1];   // 34 KB (padded)
    __shared__ float h2s[256][TN + 1];   // 17 KB
    int t = threadIdx.x;
    int b = blockIdx.y;
    int n0 = blockIdx.x * TN;
    const float* xb = xc + (size_t)b * 192 * NPTS + n0;
    for (int i = t; i < 192 * TN; i += 256) { int c = i >> 4, tn = i & 15; xcs[c][tn] = xb[c * NPTS + tn]; }
    __syncthreads();
    // h1: 512 outputs, 2 per thread
#pragma unroll
    for (int oo = 0; oo < 2; oo++) {
        int o = oo * 256 + t;
        const float* wr = wf1 + (size_t)o * 1216;
        float s = sf1[o];
        float gofv = goff[b * 512 + o];
        float acc[TN];
#pragma unroll
        for (int tn = 0; tn < TN; tn++) acc[tn] = 0.f;
        for (int c = 0; c < 192; c++) {
            float w = wr[c];
#pragma unroll
            for (int tn = 0; tn < TN; tn++) acc[tn] += w * xcs[c][tn];   // broadcast LDS read
        }
#pragma unroll
        for (int tn = 0; tn < TN; tn++) h1s[o][tn] = lrelu(acc[tn] * s + gofv);
    }
    __syncthreads();
    // h2: 256 outputs, 1 per thread
    {
        int o = t;
        const float* wr = wf2 + o * 512;
        float s = sf2[o], of = of2[o];
        float acc[TN];
#pragma unroll
        for (int tn = 0; tn < TN; tn++) acc[tn] = 0.f;
        for (int c = 0; c < 512; c++) {
            float w = wr[c];
#pragma unroll
            for (int tn = 0; tn < TN; tn++) acc[tn] += w * h1s[c][tn];
        }
#pragma unroll
        for (int tn = 0; tn < TN; tn++) h2s[o][tn] = lrelu(acc[tn] * s + of);
    }
    __syncthreads();
    // out: 13 x 16 = 208 values
    if (t < 13 * TN) {
        int o = t >> 4, tn = t & 15;
        const float* wr = wf3 + o * 256;
        float acc = 0.f;
        for (int c = 0; c < 256; c++) acc += wr[c] * h2s[c][tn];
        out[((size_t)b * 13 + o) * NPTS + n0 + tn] = acc;
    }
}

extern "C" void kernel_launch(void* const* d_in, const int* in_sizes, int n_in,
                              void* d_out, int out_size, void* d_ws, size_t ws_size,
                              hipStream_t stream) {
    const float* x    = (const float*)d_in[0];
    const float* w1_0 = (const float*)d_in[1];
    const float* s1_0 = (const float*)d_in[2];
    const float* o1_0 = (const float*)d_in[3];
    const float* w1_1 = (const float*)d_in[4];
    const float* s1_1 = (const float*)d_in[5];
    const float* o1_1 = (const float*)d_in[6];
    const float* w2_0 = (const float*)d_in[7];
    const float* s2_0 = (const float*)d_in[8];
    const float* o2_0 = (const float*)d_in[9];
    const float* w2_1 = (const float*)d_in[10];
    const float* s2_1 = (const float*)d_in[11];
    const float* o2_1 = (const float*)d_in[12];
    const float* w3_0 = (const float*)d_in[13];
    const float* s3_0 = (const float*)d_in[14];
    const float* o3_0 = (const float*)d_in[15];
    const float* w3_1 = (const float*)d_in[16];
    const float* s3_1 = (const float*)d_in[17];
    const float* o3_1 = (const float*)d_in[18];
    const float* w4   = (const float*)d_in[19];
    const float* b4   = (const float*)d_in[20];
    const float* wf1  = (const float*)d_in[21];
    const float* sf1  = (const float*)d_in[22];
    const float* of1  = (const float*)d_in[23];
    const float* wf2  = (const float*)d_in[24];
    const float* sf2  = (const float*)d_in[25];
    const float* of2  = (const float*)d_in[26];
    const float* wf3  = (const float*)d_in[27];
    // d_in[28] = k (int, always 20)

    // workspace layout (floats) — total ~18.1 MB
    float* xf123 = (float*)d_ws;                            // B*192*N = 3,145,728 f
    float* x1n   = xf123 + (size_t)NB * 192 * NPTS;         // B*64*N  = 1,048,576 f
    float* sq    = x1n + (size_t)NB * 64 * NPTS;            // B*N     = 16,384 f
    float* g     = sq + NB * NPTS;                          // B*1024  = 4,096 f
    float* goff  = g + NB * 1024;                           // B*512   = 2,048 f
    int*   idx   = (int*)(goff + NB * 512);                 // B*N*20  = 327,680 i
    (void)in_sizes; (void)n_in; (void)out_size; (void)ws_size;

    k_sqnorm<<<NB * NPTS / 256, 256, 0, stream>>>(x, sq);
    k_knn_euclid<<<NB * NPTS / 2, 256, 0, stream>>>(x, sq, idx);
    k_edge1<<<NB * NPTS / 4, 256, 0, stream>>>(x, w1_0, s1_0, o1_0, w1_1, s1_1, o1_1, idx, xf123);
    k_normalize<<<NB * NPTS / 256, 256, 0, stream>>>(xf123, x1n);
    k_knn_cos<<<NB * NPTS / 2, 256, 0, stream>>>(x1n, idx);
    k_edge23<<<NB * NPTS / 4, 256, 0, stream>>>(xf123, w2_0, s2_0, o2_0, w2_1, s2_1, o2_1, idx, xf123 + 64 * NPTS);
    k_normalize<<<NB * NPTS / 256, 256, 0, stream>>>(xf123 + 64 * NPTS, x1n);
    k_knn_cos<<<NB * NPTS / 2, 256, 0, stream>>>(x1n, idx);
    k_edge23<<<NB * NPTS / 4, 256, 0, stream>>>(xf123 + 64 * NPTS, w3_0, s3_0, o3_0, w3_1, s3_1, o3_1, idx, xf123 + 128 * NPTS);
    k_init_g<<<NB * 1024 / 256, 256, 0, stream>>>(g);
    k_w4pool<<<dim3(16, 128, NB), 256, 0, stream>>>(xf123, w4, b4, g);
    k_goff<<<NB * 512, 256, 0, stream>>>(g, wf1, sf1, of1, goff);
    k_tail<<<dim3(NPTS / TN, NB), 256, 0, stream>>>(xf123, wf1, sf1, goff, wf2, sf2, of2, wf3, (float*)d_out);
}